// Round 12
// baseline (246.368 us; speedup 1.0000x reference)
//
#include <hip/hip_runtime.h>

#define B_DIM 4
#define T_DIM 4096
#define D_DIM 2048
#define K_SEL 2048   // top_k = int(0.5 * 4096)
#define NB    2048   // linear buckets
#define CAP   512    // boundary-candidate capacity (typical count ~21)

// Module-scope scratch (deterministic: fully rewritten every launch).
__device__ __align__(16) double g_logits[B_DIM * T_DIM];
__device__ double g_partials[2 * B_DIM];

typedef float f4v __attribute__((ext_vector_type(4)));

// order-preserving map: double -> uint64 (larger key <=> larger double)
__device__ inline unsigned long long keymap(double d) {
    unsigned long long b = (unsigned long long)__double_as_longlong(d);
    return (b & 0x8000000000000000ULL) ? ~b : (b | 0x8000000000000000ULL);
}

// exclusive scan over 256 threads (4 waves); caller supplies a DEDICATED
// 4-entry buffer so no leading barrier is needed (1 barrier per scan).
__device__ inline unsigned scan256(unsigned v, volatile unsigned* wt, int tid) {
    unsigned inc = v;
    #pragma unroll
    for (int off = 1; off < 64; off <<= 1) {
        unsigned n = __shfl_up(inc, off, 64);
        if ((tid & 63) >= off) inc += n;
    }
    if ((tid & 63) == 63) wt[tid >> 6] = inc;
    __syncthreads();
    unsigned base = 0;
    for (int w = 0; w < (tid >> 6); ++w) base += wt[w];
    return base + inc - v;
}

// ---------------------------------------------------------------------------
// Fused kernel: 4096 blocks x 256 threads (4 waves, 1 token-row per wave).
// Phase 1: fp64 matvec (identical to the proven 25 us two-kernel K1 body).
// Phase 2: LAST block per batch row runs select+losses; last select finalizes.
__global__ __launch_bounds__(256) void router_fused(
    const float* __restrict__ x, const float* __restrict__ W,
    float* __restrict__ out_sel, float* __restrict__ out_gate,
    float* __restrict__ raw_out, float* __restrict__ out_loss,
    unsigned* __restrict__ ctrs)
{
    const int tid  = threadIdx.x;
    const int wid  = tid >> 6;
    const int lane = tid & 63;
    const int row  = blockIdx.x * 4 + wid;   // 16384 rows; block spans one batch
    const int b    = blockIdx.x >> 10;       // 1024 blocks per batch row

    __shared__ unsigned hist[NB];            // 8 KiB
    __shared__ unsigned long long ckey[CAP]; // 4 KiB
    __shared__ unsigned wtA[4], wtB[4], wtC[4];
    __shared__ double dtot[8];
    __shared__ int s_qb, s_multi, s_last;
    __shared__ unsigned s_rem, s_ccnt, s_needeq;
    __shared__ unsigned long long s_K;

    // ================= Phase 1: matvec (one row per wave) ==================
    {
        const f4v* xr = (const f4v*)(x + (size_t)row * D_DIM);
        const f4v* wr = (const f4v*)W;
        double a0 = 0.0, a1 = 0.0;
        #pragma unroll
        for (int j = 0; j < 8; ++j) {
            f4v a = __builtin_nontemporal_load(xr + lane + j * 64);
            f4v w = wr[lane + j * 64];
            a0 = fma((double)a.x, (double)w.x, a0);
            a0 = fma((double)a.y, (double)w.y, a0);
            a1 = fma((double)a.z, (double)w.z, a1);
            a1 = fma((double)a.w, (double)w.w, a1);
        }
        double acc = a0 + a1;
        #pragma unroll
        for (int off = 32; off; off >>= 1) acc += __shfl_down(acc, off, 64);
        if (lane == 0) {
            // agent-scope write-through: selecting block may sit on another XCD
            __hip_atomic_store(&g_logits[row], acc, __ATOMIC_RELAXED,
                               __HIP_MEMORY_SCOPE_AGENT);
            raw_out[row] = (float)acc;
        }
    }
    __syncthreads();   // all 4 waves' stores executed (vmcnt drained at barrier)
    if (tid == 0) {
        __threadfence();
        unsigned old = atomicAdd(&ctrs[b], 1u);
        s_last = (old == 1023u) ? 1 : 0;
    }
    __syncthreads();
    if (!s_last) return;

    // ====== Phase 2: select (256 threads; last block of this batch row) =====
    __threadfence();

    // issue 16 coherent loads first; zero hist under the latency
    const int t0 = tid * 16;
    double v[16];
    #pragma unroll
    for (int i = 0; i < 16; ++i)
        v[i] = __hip_atomic_load(&g_logits[(size_t)b * T_DIM + t0 + i],
                                 __ATOMIC_RELAXED, __HIP_MEMORY_SCOPE_AGENT);
    #pragma unroll
    for (int h = 0; h < NB / 256; ++h) hist[tid + h * 256] = 0;
    if (tid == 0) s_ccnt = 0;
    unsigned long long key[16];
    #pragma unroll
    for (int i = 0; i < 16; ++i) key[i] = keymap(v[i]);
    __syncthreads();                                   // B1

    // fixed-bound bucketing (logits ~ N(0,0.93^2); clamp keeps outliers safe)
    const double lo = -12.0, scale = (double)NB / 24.0;
    auto bkt = [&](double xv) -> int {
        int q = (int)((xv - lo) * scale);
        return q < 0 ? 0 : (q > NB - 1 ? NB - 1 : q);
    };

    #pragma unroll
    for (int i = 0; i < 16; ++i) atomicAdd(&hist[bkt(v[i])], 1u);
    __syncthreads();                                   // B2

    // suffix scan over buckets, descending: thread tid owns [B0, B0+8)
    const int B0 = (255 - tid) * 8;
    unsigned hc[8]; unsigned tsum = 0;
    #pragma unroll
    for (int j = 0; j < 8; ++j) { hc[j] = hist[B0 + j]; tsum += hc[j]; }
    unsigned above = scan256(tsum, wtA, tid);          // B3 (internal)
    {
        unsigned run = above;
        for (int j = 7; j >= 0; --j) {
            unsigned cnt = hc[j];
            if (run < K_SEL && run + cnt >= K_SEL) { s_qb = B0 + j; s_rem = K_SEL - run; }
            run += cnt;
        }
    }
    __syncthreads();                                   // B4

    const int qb = s_qb;
    const unsigned rem = s_rem;

    #pragma unroll
    for (int i = 0; i < 16; ++i) {
        if (bkt(v[i]) == qb) {
            unsigned slot = atomicAdd(&s_ccnt, 1u);
            if (slot < CAP) ckey[slot] = key[i];
        }
    }
    __syncthreads();                                   // B5
    const unsigned c = (s_ccnt < CAP) ? s_ccnt : CAP;

    // rem-th largest among candidates (exact 64-bit, dup-aware)
    for (unsigned j = tid; j < c; j += 256) {
        unsigned long long kj = ckey[j];
        unsigned g = 0, e = 0;
        for (unsigned u = 0; u < c; ++u) {
            unsigned long long ku = ckey[u];
            g += (ku > kj) ? 1u : 0u;
            e += (ku == kj) ? 1u : 0u;
        }
        if (g < rem && g + e >= rem) { s_K = kj; s_needeq = rem - g; s_multi = (e > 1); }
    }
    __syncthreads();                                   // B6

    const unsigned long long K = s_K;
    const unsigned needeq = s_needeq;
    const int multi = s_multi;

    unsigned eqrank = 0;
    if (multi) {   // rare: duplicate threshold keys — exact index tie-break
        unsigned eqc = 0;
        #pragma unroll
        for (int i = 0; i < 16; ++i) eqc += (key[i] == K) ? 1u : 0u;
        eqrank = scan256(eqc, wtC, tid);
        __syncthreads();
    }

    unsigned selmask = 0, selc = 0;
    {
        unsigned r = eqrank;
        #pragma unroll
        for (int i = 0; i < 16; ++i) {
            const int bq  = bkt(v[i]);
            const bool eq = (key[i] == K);
            const bool sel = (bq > qb) ||
                             (bq == qb && (key[i] > K || (eq && r < needeq)));
            if (eq) ++r;
            if (sel) { selmask |= (1u << i); ++selc; }
        }
    }
    unsigned pos = scan256(selc, wtB, tid);            // B7 (internal)

    #pragma unroll
    for (int i = 0; i < 16; ++i) {
        if (selmask & (1u << i)) {
            if (pos < K_SEL) {   // defensive
                out_sel [(size_t)b * K_SEL + pos] = (float)(t0 + i);
                out_gate[(size_t)b * K_SEL + pos] =
                    0.1f / (1.0f + __expf(-(float)v[i]));
            }
            ++pos;
        }
    }

    // losses (fp32 elementwise, fp64 accumulate); fixed lse reference m = 12
    const float m = 12.0f;
    double bce = 0.0, se = 0.0;
    #pragma unroll
    for (int i = 0; i < 16; ++i) {
        const float l   = (float)v[i];
        const float tgt = ((selmask >> i) & 1u) ? 1.0f : 0.0f;
        bce += (double)(fmaxf(l, 0.0f) - l * tgt + log1pf(__expf(-fabsf(l))));
        se  += (double)__expf(l - m);
    }
    #pragma unroll
    for (int off = 32; off; off >>= 1) {
        bce += __shfl_down(bce, off, 64);
        se  += __shfl_down(se,  off, 64);
    }
    if (lane == 0) { dtot[wid] = bce; dtot[4 + wid] = se; }
    __syncthreads();                                   // B8

    if (wid == 0) {
        double bs = (lane < 4) ? dtot[lane] : 0.0;
        double ss = (lane < 4) ? dtot[4 + lane] : 0.0;
        #pragma unroll
        for (int off = 2; off; off >>= 1) {
            bs += __shfl_down(bs, off, 64);
            ss += __shfl_down(ss, off, 64);
        }
        int last2 = 0;
        if (lane == 0) {
            double z = (double)m + log(ss);
            __hip_atomic_store(&g_partials[b], bs, __ATOMIC_RELAXED, __HIP_MEMORY_SCOPE_AGENT);
            __hip_atomic_store(&g_partials[4 + b], z, __ATOMIC_RELAXED, __HIP_MEMORY_SCOPE_AGENT);
            __threadfence();
            last2 = (atomicAdd(&ctrs[B_DIM], 1u) == 3u) ? 1 : 0;
        }
        last2 = __shfl(last2, 0, 64);
        if (last2) {   // final select block computes the two scalar losses
            __threadfence();
            double p = (lane < 8)
                ? __hip_atomic_load(&g_partials[lane], __ATOMIC_RELAXED, __HIP_MEMORY_SCOPE_AGENT)
                : 0.0;
            double bsum = (lane < 4) ? p : 0.0;
            double zz   = (lane >= 4 && lane < 8) ? p * p : 0.0;
            #pragma unroll
            for (int off = 4; off; off >>= 1) {
                bsum += __shfl_down(bsum, off, 64);
                zz   += __shfl_down(zz,   off, 64);
            }
            if (lane == 0) {
                out_loss[0] = (float)(0.001 * bsum / (double)(B_DIM * T_DIM));
                out_loss[1] = (float)(0.001 * zz / (double)B_DIM);
            }
        }
    }
}

// ---------------------------------------------------------------------------
extern "C" void kernel_launch(void* const* d_in, const int* in_sizes, int n_in,
                              void* d_out, int out_size, void* d_ws, size_t ws_size,
                              hipStream_t stream) {
    const float* x = (const float*)d_in[0];   // (4, 4096, 2048) fp32
    const float* W = (const float*)d_in[1];   // (1, 2048) fp32
    float* out = (float*)d_out;               // fp32 outputs
    unsigned* ctrs = (unsigned*)d_ws;         // 5 counters, zeroed each launch

    hipMemsetAsync(ctrs, 0, 32, stream);      // graph-capturable node

    // out layout (float elems): sel[8192] | gate[8192] | raw[16384] | aux | z
    router_fused<<<(B_DIM * T_DIM) / 4, 256, 0, stream>>>(
        x, W, out, out + 8192, out + 16384, out + 32768, ctrs);
}

// Round 13
// 34.477 us; speedup vs baseline: 7.1459x; 7.1459x over previous
//
#include <hip/hip_runtime.h>

#define B_DIM 4
#define T_DIM 4096
#define D_DIM 2048
#define K_SEL 2048   // top_k = int(0.5 * 4096)
#define NB    2048   // linear buckets
#define CAP   1024   // boundary-candidate capacity (typical count ~21)

// Module-scope scratch (deterministic: fully rewritten every launch).
__device__ __align__(16) double g_logits[B_DIM * T_DIM];
__device__ double g_partials[2 * B_DIM];
__device__ unsigned g_done_ctr;   // reset by K1 each launch

typedef float f4v __attribute__((ext_vector_type(4)));

// order-preserving map: double -> uint64 (larger key <=> larger double)
__device__ inline unsigned long long keymap(double d) {
    unsigned long long b = (unsigned long long)__double_as_longlong(d);
    return (b & 0x8000000000000000ULL) ? ~b : (b | 0x8000000000000000ULL);
}

// exclusive scan of one unsigned per thread across 1024 threads (16 waves)
__device__ inline unsigned block_excl_scan_1024(unsigned v, unsigned* wtot, int tid) {
    unsigned inc = v;
    #pragma unroll
    for (int off = 1; off < 64; off <<= 1) {
        unsigned n = __shfl_up(inc, off, 64);
        if ((tid & 63) >= off) inc += n;
    }
    __syncthreads();                       // protect wtot from previous use
    if ((tid & 63) == 63) wtot[tid >> 6] = inc;
    __syncthreads();
    unsigned base = 0;
    for (int w = 0; w < (tid >> 6); ++w) base += wtot[w];
    return base + inc - v;
}

// ---------------------------------------------------------------------------
// K1: logits[b,t] = dot(x[b,t,:], W) in fp64.  One wave per row.
// ROUND-13 single variable: all 8 x-loads staged back-to-back before any FMA
// (guaranteed 128B/lane in flight; W loads interleave with FMAs from L1).
__global__ __launch_bounds__(256) void router_matvec(
    const float* __restrict__ x, const float* __restrict__ W,
    float* __restrict__ raw_out)
{
    if (blockIdx.x == 0 && threadIdx.x == 0) g_done_ctr = 0;  // reset fuse ctr
    const int row  = blockIdx.x * 4 + (threadIdx.x >> 6);   // 16384 rows
    const int lane = threadIdx.x & 63;
    const f4v* xr = (const f4v*)(x + (size_t)row * D_DIM);
    const f4v* wr = (const f4v*)W;

    f4v a[8];
    #pragma unroll
    for (int j = 0; j < 8; ++j)
        a[j] = __builtin_nontemporal_load(xr + lane + j * 64);   // 8 in flight

    double a0 = 0.0, a1 = 0.0;
    #pragma unroll
    for (int j = 0; j < 8; ++j) {
        f4v w = wr[lane + j * 64];                               // L1-cached
        a0 = fma((double)a[j].x, (double)w.x, a0);
        a0 = fma((double)a[j].y, (double)w.y, a0);
        a1 = fma((double)a[j].z, (double)w.z, a1);
        a1 = fma((double)a[j].w, (double)w.w, a1);
    }
    double acc = a0 + a1;
    #pragma unroll
    for (int off = 32; off; off >>= 1) acc += __shfl_down(acc, off, 64);
    if (lane == 0) {
        g_logits[row] = acc;
        raw_out[row]  = (float)acc;
    }
}

// ---------------------------------------------------------------------------
// K2: per batch row (1024 threads) — fixed-bound linear-bucket select, exact
// 64-bit threshold fix-up, compaction, losses, fused finalize (last block).
// (unchanged from round 11)
__global__ __launch_bounds__(1024) void router_select(
    float* __restrict__ out_sel,
    float* __restrict__ out_gate,
    float* __restrict__ out_loss)
{
    const int b    = blockIdx.x;
    const int tid  = threadIdx.x;
    const int wid  = tid >> 6;
    const int lane = tid & 63;

    __shared__ unsigned hist[NB];              // 8 KiB
    __shared__ unsigned long long ckey[CAP];   // 8 KiB
    __shared__ unsigned wtot[16];
    __shared__ double dtot[32];
    __shared__ int s_qb, s_multi, s_last;
    __shared__ unsigned s_rem, s_ccnt, s_needeq;
    __shared__ unsigned long long s_K;

    // ---- issue global loads first; zero hist under the load latency ----
    const int t0 = tid * 4;
    const double2* gp = (const double2*)(g_logits + (size_t)b * T_DIM + t0);
    double2 d0 = gp[0], d1 = gp[1];
    hist[tid] = 0; hist[tid + 1024] = 0;
    if (tid == 0) s_ccnt = 0;
    double v[4] = { d0.x, d0.y, d1.x, d1.y };
    unsigned long long key[4];
    #pragma unroll
    for (int i = 0; i < 4; ++i) key[i] = keymap(v[i]);
    __syncthreads();

    // ---- fixed-bound bucketing: logits ~ N(0, 0.93^2), |max| ~ 3.8 ----
    const double lo = -12.0, scale = (double)NB / 24.0;
    auto bkt = [&](double xv) -> int {
        int q = (int)((xv - lo) * scale);
        return q < 0 ? 0 : (q > NB - 1 ? NB - 1 : q);
    };

    // ---- single histogram pass (low contention: ~2 elems/bucket) ----
    #pragma unroll
    for (int i = 0; i < 4; ++i) atomicAdd(&hist[bkt(v[i])], 1u);
    __syncthreads();

    // ---- suffix scan over buckets, descending: thread tid owns [B0,B0+2) ----
    const int B0 = (1023 - tid) * 2;
    unsigned hc0 = hist[B0], hc1 = hist[B0 + 1];
    unsigned above = block_excl_scan_1024(hc0 + hc1, wtot, tid);
    {
        unsigned run = above;            // counts in buckets above B0+1
        if (run < K_SEL && run + hc1 >= K_SEL) { s_qb = B0 + 1; s_rem = K_SEL - run; }
        run += hc1;
        if (run < K_SEL && run + hc0 >= K_SEL) { s_qb = B0;     s_rem = K_SEL - run; }
    }
    __syncthreads();

    const int qb = s_qb;
    const unsigned rem = s_rem;   // how many to take from boundary bucket

    // ---- gather boundary-bucket candidates ----
    #pragma unroll
    for (int i = 0; i < 4; ++i) {
        if (bkt(v[i]) == qb) {
            unsigned slot = atomicAdd(&s_ccnt, 1u);
            if (slot < CAP) ckey[slot] = key[i];
        }
    }
    __syncthreads();
    const unsigned c = (s_ccnt < CAP) ? s_ccnt : CAP;

    // ---- rem-th largest among candidates (exact 64-bit, dup-aware) ----
    if (tid < (int)c) {
        unsigned long long kj = ckey[tid];
        unsigned g = 0, e = 0;
        for (unsigned u = 0; u < c; ++u) {
            unsigned long long ku = ckey[u];
            g += (ku > kj) ? 1u : 0u;
            e += (ku == kj) ? 1u : 0u;
        }
        if (g < rem && g + e >= rem) { s_K = kj; s_needeq = rem - g; s_multi = (e > 1); }
    }
    __syncthreads();

    const unsigned long long K = s_K;
    const unsigned needeq = s_needeq;
    const int multi = s_multi;     // block-uniform

    // eq-rank scan only when the threshold key is duplicated (rare)
    unsigned eqrank = 0;
    if (multi) {
        unsigned eqc = 0;
        #pragma unroll
        for (int i = 0; i < 4; ++i) eqc += (key[i] == K) ? 1u : 0u;
        eqrank = block_excl_scan_1024(eqc, wtot, tid);
    }

    unsigned selmask = 0, selc = 0;
    {
        unsigned r = eqrank;
        #pragma unroll
        for (int i = 0; i < 4; ++i) {
            const int bq  = bkt(v[i]);
            const bool eq = (key[i] == K);
            const bool sel = (bq > qb) ||
                             (bq == qb && (key[i] > K || (eq && r < needeq)));
            if (eq) ++r;
            if (sel) { selmask |= (1u << i); ++selc; }
        }
    }
    unsigned pos = block_excl_scan_1024(selc, wtot, tid);

    #pragma unroll
    for (int i = 0; i < 4; ++i) {
        if (selmask & (1u << i)) {
            if (pos < K_SEL) {   // defensive
                out_sel [(size_t)b * K_SEL + pos] = (float)(t0 + i);
                out_gate[(size_t)b * K_SEL + pos] =
                    0.1f / (1.0f + __expf(-(float)v[i]));
            }
            ++pos;
        }
    }

    // ---- losses (fp32 elementwise, fp64 accumulate); fixed lse ref m=12 ----
    const float m = 12.0f;
    double bce = 0.0, se = 0.0;
    #pragma unroll
    for (int i = 0; i < 4; ++i) {
        const float l   = (float)v[i];
        const float tgt = ((selmask >> i) & 1u) ? 1.0f : 0.0f;
        bce += (double)(fmaxf(l, 0.0f) - l * tgt + log1pf(__expf(-fabsf(l))));
        se  += (double)__expf(l - m);
    }
    #pragma unroll
    for (int off = 32; off; off >>= 1) {
        bce += __shfl_down(bce, off, 64);
        se  += __shfl_down(se,  off, 64);
    }
    if (lane == 0) { dtot[wid] = bce; dtot[16 + wid] = se; }
    __syncthreads();

    if (wid == 0) {
        double bs = (lane < 16) ? dtot[lane] : 0.0;
        double ss = (lane < 16) ? dtot[16 + lane] : 0.0;
        #pragma unroll
        for (int off = 8; off; off >>= 1) {
            bs += __shfl_down(bs, off, 64);
            ss += __shfl_down(ss, off, 64);
        }
        if (lane == 0) {
            double z = (double)m + log(ss);
            __hip_atomic_store(&g_partials[b], bs, __ATOMIC_RELAXED, __HIP_MEMORY_SCOPE_AGENT);
            __hip_atomic_store(&g_partials[4 + b], z, __ATOMIC_RELAXED, __HIP_MEMORY_SCOPE_AGENT);
            __threadfence();
            unsigned old = atomicAdd(&g_done_ctr, 1u);
            s_last = (old == 3u) ? 1 : 0;
        }
    }
    __syncthreads();

    // fused finalize: last block, parallel partial loads + shuffle reduce
    if (s_last && wid == 0) {
        __threadfence();
        double p = (lane < 8)
            ? __hip_atomic_load(&g_partials[lane], __ATOMIC_RELAXED, __HIP_MEMORY_SCOPE_AGENT)
            : 0.0;
        double bs = (lane < 4) ? p : 0.0;          // partials[0..3] = bce sums
        double zz = (lane >= 4 && lane < 8) ? p * p : 0.0;  // partials[4..7] = z
        #pragma unroll
        for (int off = 4; off; off >>= 1) {
            bs += __shfl_down(bs, off, 64);
            zz += __shfl_down(zz, off, 64);
        }
        if (lane == 0) {
            out_loss[0] = (float)(0.001 * bs / (double)(B_DIM * T_DIM));
            out_loss[1] = (float)(0.001 * zz / (double)B_DIM);
        }
    }
}

// ---------------------------------------------------------------------------
extern "C" void kernel_launch(void* const* d_in, const int* in_sizes, int n_in,
                              void* d_out, int out_size, void* d_ws, size_t ws_size,
                              hipStream_t stream) {
    const float* x = (const float*)d_in[0];   // (4, 4096, 2048) fp32
    const float* W = (const float*)d_in[1];   // (1, 2048) fp32
    float* out = (float*)d_out;               // fp32 outputs

    // out layout (float elems): sel[8192] | gate[8192] | raw[16384] | aux | z
    router_matvec <<<(B_DIM * T_DIM) / 4, 256, 0, stream>>>(x, W, out + 16384);
    router_select <<<B_DIM, 1024, 0, stream>>>(out, out + 8192, out + 32768);
}